// Round 12
// baseline (59.200 us; speedup 1.0000x reference)
//
#include <hip/hip_runtime.h>

#define WL 512   // window_len (t and o dims)
#define NV 64    // n_var
#define LR 16    // low rank
#define NB 512   // batch
#define BB 16    // batches per k_out block
#define OO 8     // o-rows per k_out block

__device__ __forceinline__ float tanh_fast(float x) {
    // tanh(x) = 1 - 2/(exp(2x)+1); exact at +-inf saturation, ~1e-7 abs err
    float e = __expf(2.0f * x);
    return 1.0f - 2.0f / (e + 1.0f);
}

// K1: tmp[b,v,k] = sum_t tanh(g[v]*x[b,t,v]) * A[t,k]   (TRANSPOSED [b,v,k])
// grid = 512 (one block per b), block = 1024 threads (16 waves).
// Hot loop byte-identical to R7's verified version; only the epilogue changed:
// red is [tg][k][65] (pad-65 -> write stride-1 conflict-free, read (k2+v2)%32
// banks ~4-way on 16 reads only), output written [b][v][k] so K2 can read a
// lane's 16 tmp values as 4x float4. Same t-ascending sum order -> bit-identical.
__global__ __launch_bounds__(1024, 8) void k_tmp(
    const float* __restrict__ x, const float* __restrict__ gating,
    const float* __restrict__ A, float* __restrict__ tmp)
{
    __shared__ float red[16 * LR * 65];  // 66.56 KiB, 2 blocks/CU
    const int tid = threadIdx.x;
    const int b = blockIdx.x;

    const int v = tid & 63;
    const int tg = __builtin_amdgcn_readfirstlane(tid >> 6);
    const float g = gating[v];

    float acc[LR];
#pragma unroll
    for (int k = 0; k < LR; ++k) acc[k] = 0.f;

    const float* xb = x + (size_t)b * (WL * NV) + (size_t)tg * 32 * NV + v;
    const float* Abase = A + (size_t)tg * 32 * LR;

#pragma unroll 4
    for (int i = 0; i < 32; ++i) {
        const float x1 = tanh_fast(g * xb[i * NV]);      // 256B/wave, coalesced
        const float* Ar = Abase + i * LR;                // wave-uniform -> s_load
#pragma unroll
        for (int k = 0; k < LR; ++k) acc[k] = fmaf(x1, Ar[k], acc[k]);
    }

    // write partials: lanes consecutive v, stride-1 -> conflict-free
#pragma unroll
    for (int k = 0; k < LR; ++k) red[(tg * LR + k) * 65 + v] = acc[k];
    __syncthreads();

    // one (v2,k2) pair per thread; same t-order as before -> identical sums
    {
        const int p = tid;
        const int v2 = p >> 4;
        const int k2 = p & 15;
        float s = 0.f;
#pragma unroll
        for (int t = 0; t < 16; ++t) s += red[(t * LR + k2) * 65 + v2];
        tmp[(size_t)b * (LR * NV) + v2 * LR + k2] = s;   // [b][v][k], coalesced
    }
}

// K2: out[b,o,v] = x[b,o,v] + bias[o,v] + sum_k tmp[b,v,k]*B[k,o,v]
// grid = (32 b-chunks of 16) x (64 o-tiles of 8), block = 256 (4 waves)
// thread: v = tid&63, wave wv = tid>>6 owns o_local = wv*2 + {0,1}
//
// R11 fixed B-refetch (B_lds staged once) but died on occupancy: 64KB LDS +
// waves_per_eu(2,2) -> 8 waves/CU, 18% occ, latency-bound at 45us. This
// version: (a) NO T_lds — tmp now [b,v,k] so a lane's 16 values are 4x
// float4 from L2 (4 VMEM vs 16 ds_read: iter work 173->~90cy); (b) B_lds
// only = 32KB -> 4 blocks/CU; (c) waves_per_eu(4,4): 16 waves/CU AND a
// 128-VGPR budget the pinned allocator honors (R11 measured 88 granted).
// BB=16 amortizes B staging 32x (B L2 traffic 64MB). tmp+x prefetched 1
// batch ahead; 4 waves/SIMD x ~90cy covers the ~250cy L2 latency.
__global__ __attribute__((amdgpu_flat_work_group_size(256, 256),
                          amdgpu_waves_per_eu(4, 4)))
void k_out(
    const float* __restrict__ x, const float* __restrict__ bias,
    const float* __restrict__ Bm, const float* __restrict__ tmp,
    float* __restrict__ out)
{
    __shared__ float B_lds[OO * LR * NV];  // [o][k][v] 32 KiB
    const int tid = threadIdx.x;
    const int v = tid & 63;
    const int wv = tid >> 6;               // 0..3
    const int o0 = blockIdx.y * OO;
    const int b0 = blockIdx.x * BB;

    // stage B slice: 8192 floats = 2048 float4, coalesced (verified in R11)
#pragma unroll
    for (int i = 0; i < 8; ++i) {
        const int fidx = i * 256 + tid;    // float4 index 0..2047
        const int ko = fidx >> 4;          // 0..127 = (o_local, k)
        const int v4 = fidx & 15;
        const int ol = ko >> 4;            // 0..7
        const int k  = ko & 15;
        const float4 val = *(const float4*)(Bm + ((size_t)k * WL + (o0 + ol)) * NV + v4 * 4);
        *(float4*)(B_lds + ((ol * LR + k) * NV) + v4 * 4) = val;
    }
    __syncthreads();

    const int ol0 = wv * 2;
    float Breg[2][LR];
#pragma unroll
    for (int j = 0; j < 2; ++j)
#pragma unroll
        for (int k = 0; k < LR; ++k)
            Breg[j][k] = B_lds[((ol0 + j) * LR + k) * NV + v];  // stride-1, conflict-free
    float breg[2];
#pragma unroll
    for (int j = 0; j < 2; ++j) breg[j] = bias[(o0 + ol0 + j) * NV + v];

    // prefetch batch b0: tmp row (4x float4) + x residuals
    float4 t4a[4], t4b[4];
    float xra[2], xrb[2];
    {
        const float4* tb = (const float4*)(tmp + (size_t)b0 * (LR * NV) + v * LR);
#pragma unroll
        for (int q = 0; q < 4; ++q) t4a[q] = tb[q];
        const float* xb = x + (size_t)b0 * (WL * NV);
#pragma unroll
        for (int j = 0; j < 2; ++j) xra[j] = xb[(o0 + ol0 + j) * NV + v];
    }

#pragma unroll 1
    for (int bl = 0; bl < BB; ++bl) {
        const int b = b0 + bl;

        // issue next batch's loads first (hide L2/L3 latency under FMAs)
        if (bl + 1 < BB) {
            const float4* tb = (const float4*)(tmp + (size_t)(b + 1) * (LR * NV) + v * LR);
#pragma unroll
            for (int q = 0; q < 4; ++q) t4b[q] = tb[q];
            const float* xb = x + (size_t)(b + 1) * (WL * NV);
#pragma unroll
            for (int j = 0; j < 2; ++j) xrb[j] = xb[(o0 + ol0 + j) * NV + v];
        }

        float tr[LR];
        tr[0]=t4a[0].x; tr[1]=t4a[0].y; tr[2]=t4a[0].z; tr[3]=t4a[0].w;
        tr[4]=t4a[1].x; tr[5]=t4a[1].y; tr[6]=t4a[1].z; tr[7]=t4a[1].w;
        tr[8]=t4a[2].x; tr[9]=t4a[2].y; tr[10]=t4a[2].z; tr[11]=t4a[2].w;
        tr[12]=t4a[3].x; tr[13]=t4a[3].y; tr[14]=t4a[3].z; tr[15]=t4a[3].w;

        float* ob = out + (size_t)b * (WL * NV);
#pragma unroll
        for (int j = 0; j < 2; ++j) {
            float acc = breg[j];
#pragma unroll
            for (int k = 0; k < LR; ++k) acc += tr[k] * Breg[j][k];
            ob[(o0 + ol0 + j) * NV + v] = xra[j] + acc;
        }

        if (bl + 1 < BB) {
#pragma unroll
            for (int q = 0; q < 4; ++q) t4a[q] = t4b[q];
            xra[0] = xrb[0]; xra[1] = xrb[1];
        }
    }
}

extern "C" void kernel_launch(void* const* d_in, const int* in_sizes, int n_in,
                              void* d_out, int out_size, void* d_ws, size_t ws_size,
                              hipStream_t stream) {
    const float* x      = (const float*)d_in[0];  // [512,512,64,1]
    const float* gating = (const float*)d_in[1];  // [64]
    const float* bias   = (const float*)d_in[2];  // [512,64]
    const float* A      = (const float*)d_in[3];  // [512,16]
    const float* Bm     = (const float*)d_in[4];  // [16,512,64]
    float* out = (float*)d_out;
    float* tmp = (float*)d_ws;                    // 2 MiB scratch ([b,v,k])

    k_tmp<<<NB, 1024, 0, stream>>>(x, gating, A, tmp);
    k_out<<<dim3(32, 64), 256, 0, stream>>>(x, bias, Bm, tmp, out);
}